// Round 5
// baseline (222.128 us; speedup 1.0000x reference)
//
#include <hip/hip_runtime.h>
#include <hip/hip_bf16.h>

#define EPSF 1e-5f

typedef __attribute__((ext_vector_type(8))) short bf16x8;
typedef __attribute__((ext_vector_type(4))) short bf16x4;
typedef __attribute__((ext_vector_type(4))) float f32x4;

constexpr int B_ = 2, N_ = 16384;
constexpr int HSTR = 72;
constexpr int RSTR = 72;
constexpr int PPW  = 4;    // points per wave
constexpr int PPB  = 16;   // points per block
constexpr size_t FB_BYTES = (size_t)B_ * N_ * 64 * 2;  // 4 MiB bf16 features
constexpr size_t PP_BYTES = (size_t)B_ * N_ * 16;      // 512 KiB padded points
constexpr size_t WS_NEED  = FB_BYTES + PP_BYTES;

__device__ __forceinline__ short f2bf(float f) {
    __hip_bfloat16 h = __float2bfloat16(f);
    short s;
    __builtin_memcpy(&s, &h, 2);
    return s;
}
__device__ __forceinline__ float bf2f(short s) {
    unsigned int u = ((unsigned int)(unsigned short)s) << 16;
    float f;
    __builtin_memcpy(&f, &u, 4);
    return f;
}

// ---------- prep: features -> bf16 rows (128B), points -> padded float4 ----------
__global__ __launch_bounds__(256) void prep_kernel(
    const float* __restrict__ feat, const float* __restrict__ pts,
    short* __restrict__ fb, float* __restrict__ pp)
{
    const int i = blockIdx.x * 256 + threadIdx.x;
    if (i < B_ * N_ * 64 / 4) {
        const f32x4 v = ((const f32x4*)feat)[i];
        bf16x4 o;
        #pragma unroll
        for (int j = 0; j < 4; ++j) o[j] = f2bf(v[j]);
        ((bf16x4*)fb)[i] = o;
    }
    if (i < B_ * N_) {
        f32x4 o = { pts[3 * i], pts[3 * i + 1], pts[3 * i + 2], 0.f };
        ((f32x4*)pp)[i] = o;
    }
}

// ---------- main: channel-interleaved MFMA, bf16 gathers, float4 coord gathers ----------
__global__ __launch_bounds__(256) void bridgenet_mfma5(
    const short* __restrict__ fb,      // bf16 features, rows of 64
    const float* __restrict__ pp,      // padded float4 points
    const int*   __restrict__ gidx,
    const float* __restrict__ Wpos,
    const float* __restrict__ bposv,
    const float* __restrict__ bn1g, const float* __restrict__ bn1b,
    const float* __restrict__ bn1m, const float* __restrict__ bn1v,
    const float* __restrict__ Wgcm,
    const float* __restrict__ bgcm,
    const float* __restrict__ bn2g, const float* __restrict__ bn2b,
    const float* __restrict__ bn2m, const float* __restrict__ bn2v,
    const float* __restrict__ Watt,
    const float* __restrict__ batt,
    const float* __restrict__ Wout,
    const float* __restrict__ bout,
    const float* __restrict__ lng, const float* __restrict__ lnb,
    float* __restrict__ out)
{
    __shared__ __align__(16) short hbuf[4][32 * HSTR];
    __shared__ __align__(16) short resstage[PPB * RSTR];

    const int t    = threadIdx.x;
    const int w    = t >> 6;
    const int l    = t & 63;
    const int l15  = l & 15;
    const int quad = l >> 4;
    const int c4   = l15 * 4;

    // ---------- constant fragments ----------
    bf16x8 bposf[4];
    #pragma unroll
    for (int nt = 0; nt < 4; ++nt) {
        const int c = c4 + nt;
        #pragma unroll
        for (int j = 0; j < 8; ++j) {
            const int g = quad * 8 + j;
            bposf[nt][j] = f2bf(g < 10 ? Wpos[c * 10 + g] : 0.f);
        }
    }
    bf16x8 b2f[4][2];
    #pragma unroll
    for (int nt = 0; nt < 4; ++nt)
        #pragma unroll
        for (int ks = 0; ks < 2; ++ks) {
            const int d = c4 + nt;
            #pragma unroll
            for (int j = 0; j < 8; ++j)
                b2f[nt][ks][j] = f2bf(Wgcm[d * 64 + ks * 32 + quad * 8 + j]);
        }
    f32x4 ps1, pb1, ps2, pb2;
    {
        const f32x4 g1 = *(const f32x4*)(bn1g + c4);
        const f32x4 b1 = *(const f32x4*)(bn1b + c4);
        const f32x4 m1 = *(const f32x4*)(bn1m + c4);
        const f32x4 v1 = *(const f32x4*)(bn1v + c4);
        const f32x4 bp = *(const f32x4*)(bposv + c4);
        const f32x4 g2 = *(const f32x4*)(bn2g + c4);
        const f32x4 b2 = *(const f32x4*)(bn2b + c4);
        const f32x4 m2 = *(const f32x4*)(bn2m + c4);
        const f32x4 v2 = *(const f32x4*)(bn2v + c4);
        const f32x4 bg = *(const f32x4*)(bgcm + c4);
        #pragma unroll
        for (int j = 0; j < 4; ++j) {
            ps1[j] = g1[j] * rsqrtf(v1[j] + EPSF);
            pb1[j] = ps1[j] * (bp[j] - m1[j]) + b1[j];
            ps2[j] = g2[j] * rsqrtf(v2[j] + EPSF);
            pb2[j] = ps2[j] * (bg[j] - m2[j]) + b2[j];
        }
    }
    float wat[2][4];
    #pragma unroll
    for (int mt = 0; mt < 2; ++mt)
        #pragma unroll
        for (int r = 0; r < 4; ++r)
            wat[mt][r] = Watt[mt * 16 + quad * 4 + r];
    const float battv = batt[0];

    const f32x4 zero4 = {0.f, 0.f, 0.f, 0.f};
    short* hb = hbuf[w];

    const int base = blockIdx.x * PPB + w * PPW;
    const int bb   = (base >> 14) * N_;   // wave-uniform batch base (blocks don't straddle batches)

    // ---------- pipeline state ----------
    int    giv[PPW][2];
    f32x4  xi4[PPW];
    f32x4  pj4[PPW][2];
    bf16x4 f4[PPW][2][4];
    bf16x4 resid[PPW];

    auto loadIdx = [&](int i) {
        const int pt = base + i;
        giv[i][0] = gidx[(size_t)pt * 32 + l15];
        giv[i][1] = gidx[(size_t)pt * 32 + 16 + l15];
    };
    auto loadGather = [&](int i) {
        const int pt = base + i;
        xi4[i]   = *(const f32x4*)(pp + (size_t)pt * 4);
        resid[i] = *(const bf16x4*)(fb + (size_t)pt * 64 + c4);
        #pragma unroll
        for (int mt = 0; mt < 2; ++mt)
            pj4[i][mt] = *(const f32x4*)(pp + (size_t)(bb + giv[i][mt]) * 4);
        #pragma unroll
        for (int mt = 0; mt < 2; ++mt)
            #pragma unroll
            for (int r = 0; r < 4; ++r) {
                const int gs = __shfl(giv[i][mt], quad * 4 + r);
                f4[i][mt][r] = *(const bf16x4*)(fb + (size_t)(bb + gs) * 64 + c4);
            }
    };

    loadIdx(0);
    loadIdx(1);
    loadGather(0);

    #pragma unroll
    for (int i = 0; i < PPW; ++i) {
        if (i + 2 < PPW) loadIdx(i + 2);
        if (i + 1 < PPW) loadGather(i + 1);

        // --- geo A-frags (k = mt*16 + l15, g = quad*8+j) ---
        bf16x8 ageo[2];
        #pragma unroll
        for (int mt = 0; mt < 2; ++mt) {
            const float dx = xi4[i][0] - pj4[i][mt][0];
            const float dy = xi4[i][1] - pj4[i][mt][1];
            const float dz = xi4[i][2] - pj4[i][mt][2];
            const float dist = sqrtf(dx * dx + dy * dy + dz * dz);
            bf16x8 fr = {0, 0, 0, 0, 0, 0, 0, 0};
            if (quad == 0) {
                fr[0] = f2bf(xi4[i][0]);    fr[1] = f2bf(xi4[i][1]); fr[2] = f2bf(xi4[i][2]);
                fr[3] = f2bf(pj4[i][mt][0]); fr[4] = f2bf(pj4[i][mt][1]); fr[5] = f2bf(pj4[i][mt][2]);
                fr[6] = f2bf(dx);            fr[7] = f2bf(dy);
            } else if (quad == 1) {
                fr[0] = f2bf(dz);            fr[1] = f2bf(dist);
            }
            ageo[mt] = fr;
        }

        // --- pos-MLP MFMA ---
        f32x4 acc1[2][4];
        #pragma unroll
        for (int mt = 0; mt < 2; ++mt)
            #pragma unroll
            for (int nt = 0; nt < 4; ++nt)
                acc1[mt][nt] = __builtin_amdgcn_mfma_f32_16x16x32_bf16(
                    ageo[mt], bposf[nt], zero4, 0, 0, 0);

        // --- epilogue 1: bn1+relu + bf16 feature add, packed b64 writes ---
        #pragma unroll
        for (int mt = 0; mt < 2; ++mt)
            #pragma unroll
            for (int r = 0; r < 4; ++r) {
                const int k = mt * 16 + quad * 4 + r;
                bf16x4 hv;
                #pragma unroll
                for (int j = 0; j < 4; ++j) {
                    const float e = fmaxf(ps1[j] * acc1[mt][j][r] + pb1[j], 0.f);
                    hv[j] = f2bf(bf2f(f4[i][mt][r][j]) + e);
                }
                *(bf16x4*)&hb[k * HSTR + c4] = hv;
            }

        // --- GCM: A-frags from LDS, 16 MFMAs ---
        bf16x8 a2[2][2];
        #pragma unroll
        for (int mt = 0; mt < 2; ++mt)
            #pragma unroll
            for (int ks = 0; ks < 2; ++ks)
                a2[mt][ks] = *(const bf16x8*)&hb[(mt * 16 + l15) * HSTR + ks * 32 + quad * 8];
        f32x4 acc2[2][4];
        #pragma unroll
        for (int mt = 0; mt < 2; ++mt)
            #pragma unroll
            for (int nt = 0; nt < 4; ++nt) {
                f32x4 a = __builtin_amdgcn_mfma_f32_16x16x32_bf16(a2[mt][0], b2f[nt][0], zero4, 0, 0, 0);
                acc2[mt][nt] = __builtin_amdgcn_mfma_f32_16x16x32_bf16(a2[mt][1], b2f[nt][1], a, 0, 0, 0);
            }

        // --- epilogue 2: bn2+relu, attention softmax (shift-invariant, no max-sub) ---
        float res[4];
        {
            float sp[4], mk[4];
            #pragma unroll
            for (int nt = 0; nt < 4; ++nt) {
                sp[nt] = 0.f; mk[nt] = 0.f;
                #pragma unroll
                for (int mt = 0; mt < 2; ++mt)
                    #pragma unroll
                    for (int r = 0; r < 4; ++r) {
                        const float h2 = fmaxf(ps2[nt] * acc2[mt][nt][r] + pb2[nt], 0.f);
                        sp[nt] += h2 * wat[mt][r];
                        mk[nt] = fmaxf(mk[nt], h2);
                    }
                sp[nt] += __shfl_xor(sp[nt], 16);
                sp[nt] += __shfl_xor(sp[nt], 32);
                mk[nt] = fmaxf(mk[nt], __shfl_xor(mk[nt], 16));
                mk[nt] = fmaxf(mk[nt], __shfl_xor(mk[nt], 32));
            }
            float e[4], s = 0.f;
            #pragma unroll
            for (int nt = 0; nt < 4; ++nt) { e[nt] = __expf(sp[nt] + battv); s += e[nt]; }
            #pragma unroll
            for (int o = 1; o < 16; o <<= 1) s += __shfl_xor(s, o);
            const float inv = 1.f / s;
            #pragma unroll
            for (int nt = 0; nt < 4; ++nt)
                res[nt] = e[nt] * inv * mk[nt] + bf2f(resid[i][nt]);
        }
        if (quad == 0) {
            bf16x4 rv;
            #pragma unroll
            for (int j = 0; j < 4; ++j) rv[j] = f2bf(res[j]);
            *(bf16x4*)&resstage[(w * PPW + i) * RSTR + c4] = rv;
        }
    }

    __syncthreads();

    // ---------- phase D: batched out-matmul (16 pts) + LayerNorm + relu ----------
    bf16x8 b3f[4][2];
    #pragma unroll
    for (int nt = 0; nt < 4; ++nt)
        #pragma unroll
        for (int ks = 0; ks < 2; ++ks) {
            const int o = c4 + nt;
            #pragma unroll
            for (int j = 0; j < 8; ++j)
                b3f[nt][ks][j] = f2bf(Wout[o * 64 + ks * 32 + quad * 8 + j]);
        }
    const f32x4 lngv  = *(const f32x4*)(lng + c4);
    const f32x4 lnbv  = *(const f32x4*)(lnb + c4);
    const f32x4 boutv = *(const f32x4*)(bout + c4);

    bf16x8 a3[2];
    #pragma unroll
    for (int ks = 0; ks < 2; ++ks)
        a3[ks] = *(const bf16x8*)&resstage[l15 * RSTR + ks * 32 + quad * 8];
    f32x4 acc3[4];
    #pragma unroll
    for (int nt = 0; nt < 4; ++nt) {
        f32x4 a = __builtin_amdgcn_mfma_f32_16x16x32_bf16(a3[0], b3f[nt][0], zero4, 0, 0, 0);
        acc3[nt] = __builtin_amdgcn_mfma_f32_16x16x32_bf16(a3[1], b3f[nt][1], a, 0, 0, 0);
    }
    float y[4], s = 0.f;
    #pragma unroll
    for (int nt = 0; nt < 4; ++nt) { y[nt] = acc3[nt][w] + boutv[nt]; s += y[nt]; }
    #pragma unroll
    for (int o = 1; o < 16; o <<= 1) s += __shfl_xor(s, o);
    const float mu = s * (1.f / 64.f);
    float dv[4], v2 = 0.f;
    #pragma unroll
    for (int nt = 0; nt < 4; ++nt) { dv[nt] = y[nt] - mu; v2 += dv[nt] * dv[nt]; }
    #pragma unroll
    for (int o = 1; o < 16; o <<= 1) v2 += __shfl_xor(v2, o);
    const float rs = rsqrtf(v2 * (1.f / 64.f) + EPSF);
    const int pto = blockIdx.x * PPB + quad * 4 + w;
    f32x4 ov;
    #pragma unroll
    for (int nt = 0; nt < 4; ++nt)
        ov[nt] = fmaxf(lngv[nt] * dv[nt] * rs + lnbv[nt], 0.f);
    *(f32x4*)(out + (size_t)pto * 64 + c4) = ov;
}

// ---------- fallback (R4 kernel) if workspace is too small ----------
__global__ __launch_bounds__(256) void bridgenet_fallback(
    const float* __restrict__ points, const float* __restrict__ features,
    const int* __restrict__ gidx, const float* __restrict__ Wpos,
    const float* __restrict__ bposv,
    const float* __restrict__ bn1g, const float* __restrict__ bn1b,
    const float* __restrict__ bn1m, const float* __restrict__ bn1v,
    const float* __restrict__ Wgcm, const float* __restrict__ bgcm,
    const float* __restrict__ bn2g, const float* __restrict__ bn2b,
    const float* __restrict__ bn2m, const float* __restrict__ bn2v,
    const float* __restrict__ Watt, const float* __restrict__ batt,
    const float* __restrict__ Wout, const float* __restrict__ bout,
    const float* __restrict__ lng, const float* __restrict__ lnb,
    float* __restrict__ out)
{
    __shared__ __align__(16) short hbuf[4][32 * HSTR];
    __shared__ __align__(16) short resstage[32 * RSTR];
    const int t = threadIdx.x, w = t >> 6, l = t & 63, l15 = l & 15, quad = l >> 4;
    const int c4 = l15 * 4;
    bf16x8 bposf[4];
    #pragma unroll
    for (int nt = 0; nt < 4; ++nt)
        #pragma unroll
        for (int j = 0; j < 8; ++j) {
            const int g = quad * 8 + j;
            bposf[nt][j] = f2bf(g < 10 ? Wpos[(c4 + nt) * 10 + g] : 0.f);
        }
    bf16x8 b2f[4][2];
    #pragma unroll
    for (int nt = 0; nt < 4; ++nt)
        #pragma unroll
        for (int ks = 0; ks < 2; ++ks)
            #pragma unroll
            for (int j = 0; j < 8; ++j)
                b2f[nt][ks][j] = f2bf(Wgcm[(c4 + nt) * 64 + ks * 32 + quad * 8 + j]);
    f32x4 ps1, pb1, ps2, pb2;
    #pragma unroll
    for (int j = 0; j < 4; ++j) {
        const int c = c4 + j;
        ps1[j] = bn1g[c] * rsqrtf(bn1v[c] + EPSF);
        pb1[j] = ps1[j] * (bposv[c] - bn1m[c]) + bn1b[c];
        ps2[j] = bn2g[c] * rsqrtf(bn2v[c] + EPSF);
        pb2[j] = ps2[j] * (bgcm[c] - bn2m[c]) + bn2b[c];
    }
    float wat[2][4];
    #pragma unroll
    for (int mt = 0; mt < 2; ++mt)
        #pragma unroll
        for (int r = 0; r < 4; ++r) wat[mt][r] = Watt[mt * 16 + quad * 4 + r];
    const float battv = batt[0];
    const f32x4 zero4 = {0.f, 0.f, 0.f, 0.f};
    short* hb = hbuf[w];
    const int bb = (int)((blockIdx.x * 32) >> 14) * N_;
    const int base = blockIdx.x * 32 + w * 8;
    for (int i = 0; i < 8; ++i) {
        const int pt = base + i;
        int giv[2] = { gidx[(size_t)pt * 32 + l15], gidx[(size_t)pt * 32 + 16 + l15] };
        const f32x4 resid = *(const f32x4*)(features + (size_t)pt * 64 + c4);
        const float xi0 = points[(size_t)pt * 3], xi1 = points[(size_t)pt * 3 + 1], xi2 = points[(size_t)pt * 3 + 2];
        bf16x8 ageo[2]; f32x4 f4[2][4];
        #pragma unroll
        for (int mt = 0; mt < 2; ++mt) {
            const float* ppt = points + (size_t)(bb + giv[mt]) * 3;
            const float px = ppt[0], py = ppt[1], pz = ppt[2];
            const float dx = xi0 - px, dy = xi1 - py, dz = xi2 - pz;
            const float dist = sqrtf(dx * dx + dy * dy + dz * dz);
            bf16x8 fr = {0,0,0,0,0,0,0,0};
            if (quad == 0) { fr[0]=f2bf(xi0); fr[1]=f2bf(xi1); fr[2]=f2bf(xi2); fr[3]=f2bf(px); fr[4]=f2bf(py); fr[5]=f2bf(pz); fr[6]=f2bf(dx); fr[7]=f2bf(dy); }
            else if (quad == 1) { fr[0]=f2bf(dz); fr[1]=f2bf(dist); }
            ageo[mt] = fr;
            #pragma unroll
            for (int r = 0; r < 4; ++r) {
                const int gs = __shfl(giv[mt], quad * 4 + r);
                f4[mt][r] = *(const f32x4*)(features + (size_t)(bb + gs) * 64 + c4);
            }
        }
        f32x4 acc1[2][4];
        #pragma unroll
        for (int mt = 0; mt < 2; ++mt)
            #pragma unroll
            for (int nt = 0; nt < 4; ++nt)
                acc1[mt][nt] = __builtin_amdgcn_mfma_f32_16x16x32_bf16(ageo[mt], bposf[nt], zero4, 0, 0, 0);
        #pragma unroll
        for (int mt = 0; mt < 2; ++mt)
            #pragma unroll
            for (int r = 0; r < 4; ++r) {
                const int k = mt * 16 + quad * 4 + r;
                bf16x4 hv;
                #pragma unroll
                for (int j = 0; j < 4; ++j)
                    hv[j] = f2bf(f4[mt][r][j] + fmaxf(ps1[j] * acc1[mt][j][r] + pb1[j], 0.f));
                *(bf16x4*)&hb[k * HSTR + c4] = hv;
            }
        bf16x8 a2[2][2];
        #pragma unroll
        for (int mt = 0; mt < 2; ++mt)
            #pragma unroll
            for (int ks = 0; ks < 2; ++ks)
                a2[mt][ks] = *(const bf16x8*)&hb[(mt * 16 + l15) * HSTR + ks * 32 + quad * 8];
        f32x4 acc2[2][4];
        #pragma unroll
        for (int mt = 0; mt < 2; ++mt)
            #pragma unroll
            for (int nt = 0; nt < 4; ++nt) {
                f32x4 a = __builtin_amdgcn_mfma_f32_16x16x32_bf16(a2[mt][0], b2f[nt][0], zero4, 0, 0, 0);
                acc2[mt][nt] = __builtin_amdgcn_mfma_f32_16x16x32_bf16(a2[mt][1], b2f[nt][1], a, 0, 0, 0);
            }
        float res[4];
        {
            float sp[4], mk[4];
            #pragma unroll
            for (int nt = 0; nt < 4; ++nt) {
                sp[nt] = 0.f; mk[nt] = 0.f;
                #pragma unroll
                for (int mt = 0; mt < 2; ++mt)
                    #pragma unroll
                    for (int r = 0; r < 4; ++r) {
                        const float h2 = fmaxf(ps2[nt] * acc2[mt][nt][r] + pb2[nt], 0.f);
                        sp[nt] += h2 * wat[mt][r]; mk[nt] = fmaxf(mk[nt], h2);
                    }
                sp[nt] += __shfl_xor(sp[nt], 16); sp[nt] += __shfl_xor(sp[nt], 32);
                mk[nt] = fmaxf(mk[nt], __shfl_xor(mk[nt], 16));
                mk[nt] = fmaxf(mk[nt], __shfl_xor(mk[nt], 32));
            }
            float e[4], s = 0.f;
            #pragma unroll
            for (int nt = 0; nt < 4; ++nt) { e[nt] = __expf(sp[nt] + battv); s += e[nt]; }
            #pragma unroll
            for (int o = 1; o < 16; o <<= 1) s += __shfl_xor(s, o);
            const float inv = 1.f / s;
            #pragma unroll
            for (int nt = 0; nt < 4; ++nt) res[nt] = e[nt] * inv * mk[nt] + resid[nt];
        }
        if (quad == 0) {
            bf16x4 rv;
            #pragma unroll
            for (int j = 0; j < 4; ++j) rv[j] = f2bf(res[j]);
            *(bf16x4*)&resstage[(w * 8 + i) * RSTR + c4] = rv;
        }
    }
    __syncthreads();
    bf16x8 b3f[4][2];
    #pragma unroll
    for (int nt = 0; nt < 4; ++nt)
        #pragma unroll
        for (int ks = 0; ks < 2; ++ks)
            #pragma unroll
            for (int j = 0; j < 8; ++j)
                b3f[nt][ks][j] = f2bf(Wout[(c4 + nt) * 64 + ks * 32 + quad * 8 + j]);
    const f32x4 lngv = *(const f32x4*)(lng + c4);
    const f32x4 lnbv = *(const f32x4*)(lnb + c4);
    const f32x4 boutv = *(const f32x4*)(bout + c4);
    #pragma unroll
    for (int mt = 0; mt < 2; ++mt) {
        bf16x8 a3[2];
        #pragma unroll
        for (int ks = 0; ks < 2; ++ks)
            a3[ks] = *(const bf16x8*)&resstage[(mt * 16 + l15) * RSTR + ks * 32 + quad * 8];
        f32x4 acc3[4];
        #pragma unroll
        for (int nt = 0; nt < 4; ++nt) {
            f32x4 a = __builtin_amdgcn_mfma_f32_16x16x32_bf16(a3[0], b3f[nt][0], zero4, 0, 0, 0);
            acc3[nt] = __builtin_amdgcn_mfma_f32_16x16x32_bf16(a3[1], b3f[nt][1], a, 0, 0, 0);
        }
        float y[4], s = 0.f;
        #pragma unroll
        for (int nt = 0; nt < 4; ++nt) { y[nt] = acc3[nt][w] + boutv[nt]; s += y[nt]; }
        #pragma unroll
        for (int o = 1; o < 16; o <<= 1) s += __shfl_xor(s, o);
        const float mu = s * (1.f / 64.f);
        float dv[4], v2 = 0.f;
        #pragma unroll
        for (int nt = 0; nt < 4; ++nt) { dv[nt] = y[nt] - mu; v2 += dv[nt] * dv[nt]; }
        #pragma unroll
        for (int o = 1; o < 16; o <<= 1) v2 += __shfl_xor(v2, o);
        const float rs = rsqrtf(v2 * (1.f / 64.f) + EPSF);
        const int pto = blockIdx.x * 32 + mt * 16 + quad * 4 + w;
        f32x4 ov;
        #pragma unroll
        for (int nt = 0; nt < 4; ++nt) ov[nt] = fmaxf(lngv[nt] * dv[nt] * rs + lnbv[nt], 0.f);
        *(f32x4*)(out + (size_t)pto * 64 + c4) = ov;
    }
}

extern "C" void kernel_launch(void* const* d_in, const int* in_sizes, int n_in,
                              void* d_out, int out_size, void* d_ws, size_t ws_size,
                              hipStream_t stream) {
    const float* points   = (const float*)d_in[0];
    const float* features = (const float*)d_in[1];
    const int*   gidxp    = (const int*)d_in[2];
    if (ws_size >= WS_NEED) {
        short* fb = (short*)d_ws;
        float* pp = (float*)((char*)d_ws + FB_BYTES);
        hipLaunchKernelGGL(prep_kernel, dim3(2048), dim3(256), 0, stream,
                           features, points, fb, pp);
        hipLaunchKernelGGL(bridgenet_mfma5, dim3((B_ * N_) / PPB), dim3(256), 0, stream,
            fb, pp, gidxp,
            (const float*)d_in[3],  (const float*)d_in[4],
            (const float*)d_in[5],  (const float*)d_in[6],  (const float*)d_in[7],  (const float*)d_in[8],
            (const float*)d_in[9],  (const float*)d_in[10],
            (const float*)d_in[11], (const float*)d_in[12], (const float*)d_in[13], (const float*)d_in[14],
            (const float*)d_in[15], (const float*)d_in[16],
            (const float*)d_in[17], (const float*)d_in[18],
            (const float*)d_in[19], (const float*)d_in[20],
            (float*)d_out);
    } else {
        hipLaunchKernelGGL(bridgenet_fallback, dim3((B_ * N_) / 32), dim3(256), 0, stream,
            points, features, gidxp,
            (const float*)d_in[3],  (const float*)d_in[4],
            (const float*)d_in[5],  (const float*)d_in[6],  (const float*)d_in[7],  (const float*)d_in[8],
            (const float*)d_in[9],  (const float*)d_in[10],
            (const float*)d_in[11], (const float*)d_in[12], (const float*)d_in[13], (const float*)d_in[14],
            (const float*)d_in[15], (const float*)d_in[16],
            (const float*)d_in[17], (const float*)d_in[18],
            (const float*)d_in[19], (const float*)d_in[20],
            (float*)d_out);
    }
}

// Round 6
// 174.862 us; speedup vs baseline: 1.2703x; 1.2703x over previous
//
#include <hip/hip_runtime.h>
#include <hip/hip_bf16.h>

#define EPSF 1e-5f

typedef __attribute__((ext_vector_type(8))) short bf16x8;
typedef __attribute__((ext_vector_type(4))) float f32x4;
typedef __attribute__((ext_vector_type(2))) unsigned int u32x2;
typedef __attribute__((ext_vector_type(4))) unsigned int u32x4;

constexpr int B_ = 2, N_ = 16384;
constexpr int HSTR = 72;   // hbuf row stride (bf16 elems)
constexpr int RSTR = 72;
constexpr int PPW  = 4;    // points per wave
constexpr int PPB  = 16;   // points per block
constexpr size_t PP_BYTES = (size_t)B_ * N_ * 16;   // 512 KiB padded points

__device__ __forceinline__ short f2bf(float f) {
    __hip_bfloat16 h = __float2bfloat16(f);
    short s; __builtin_memcpy(&s, &h, 2); return s;
}
// packed f32x2 -> bf16x2 (v_cvt_pk_bf16_f32)
__device__ __forceinline__ unsigned int pkbf(float a, float b) {
    float2 f2; f2.x = a; f2.y = b;
    __hip_bfloat162 h = __float22bfloat162_rn(f2);
    unsigned int u; __builtin_memcpy(&u, &h, 4); return u;
}

// prep: points -> padded float4 (one dwordx4 gather instead of 3 divergent dwords)
__global__ __launch_bounds__(256) void prep_points(
    const float* __restrict__ pts, float* __restrict__ pp)
{
    const int i = blockIdx.x * 256 + threadIdx.x;
    if (i < B_ * N_) {
        f32x4 o = { pts[3 * i], pts[3 * i + 1], pts[3 * i + 2], 0.f };
        ((f32x4*)pp)[i] = o;
    }
}

// Channel interleave: MFMA tile nt / column n -> channel c = n*4 + nt, so one
// lane's 4 tiles cover channels l15*4..+3 (float4 gathers, b64 LDS writes).
// GCM/out weight B-frags live in LDS (staged by wave 0) to cut VGPRs -> TLP.
template<bool PAD>
__global__ __launch_bounds__(256) void bridgenet6(
    const float* __restrict__ points,     // raw (PAD=false)
    const float* __restrict__ pp,         // padded float4 (PAD=true)
    const float* __restrict__ features,
    const int*   __restrict__ gidx,
    const float* __restrict__ Wpos,
    const float* __restrict__ bposv,
    const float* __restrict__ bn1g, const float* __restrict__ bn1b,
    const float* __restrict__ bn1m, const float* __restrict__ bn1v,
    const float* __restrict__ Wgcm,
    const float* __restrict__ bgcm,
    const float* __restrict__ bn2g, const float* __restrict__ bn2b,
    const float* __restrict__ bn2m, const float* __restrict__ bn2v,
    const float* __restrict__ Watt,
    const float* __restrict__ batt,
    const float* __restrict__ Wout,
    const float* __restrict__ bout,
    const float* __restrict__ lng, const float* __restrict__ lnb,
    float* __restrict__ out)
{
    __shared__ __align__(16) short hbuf[4][32 * HSTR];
    __shared__ __align__(16) short resstage[PPB * RSTR];
    __shared__ __align__(16) short wb2[8 * 64 * 8];   // GCM B-frags: (nt*2+ks, lane, 8)
    __shared__ __align__(16) short wb3[8 * 64 * 8];   // out B-frags

    const int t    = threadIdx.x;
    const int w    = t >> 6;
    const int l    = t & 63;
    const int l15  = l & 15;
    const int quad = l >> 4;
    const int c4   = l15 * 4;

    // ---- wave 0 stages the loop-invariant weight fragments into LDS ----
    if (w == 0) {
        #pragma unroll
        for (int nt = 0; nt < 4; ++nt)
            #pragma unroll
            for (int ks = 0; ks < 2; ++ks) {
                bf16x8 f2, f3;
                #pragma unroll
                for (int j = 0; j < 8; ++j) {
                    f2[j] = f2bf(Wgcm[(c4 + nt) * 64 + ks * 32 + quad * 8 + j]);
                    f3[j] = f2bf(Wout[(c4 + nt) * 64 + ks * 32 + quad * 8 + j]);
                }
                *(bf16x8*)&wb2[((nt * 2 + ks) * 64 + l) * 8] = f2;
                *(bf16x8*)&wb3[((nt * 2 + ks) * 64 + l) * 8] = f3;
            }
    }

    // ---- per-wave constant state (kept lean) ----
    bf16x8 bposf[4];
    #pragma unroll
    for (int nt = 0; nt < 4; ++nt) {
        const int c = c4 + nt;
        #pragma unroll
        for (int j = 0; j < 8; ++j) {
            const int g = quad * 8 + j;
            bposf[nt][j] = f2bf(g < 10 ? Wpos[c * 10 + g] : 0.f);
        }
    }
    f32x4 ps1, pb1, ps2, pb2;
    {
        const f32x4 g1 = *(const f32x4*)(bn1g + c4);
        const f32x4 b1 = *(const f32x4*)(bn1b + c4);
        const f32x4 m1 = *(const f32x4*)(bn1m + c4);
        const f32x4 v1 = *(const f32x4*)(bn1v + c4);
        const f32x4 bp = *(const f32x4*)(bposv + c4);
        const f32x4 g2 = *(const f32x4*)(bn2g + c4);
        const f32x4 b2 = *(const f32x4*)(bn2b + c4);
        const f32x4 m2 = *(const f32x4*)(bn2m + c4);
        const f32x4 v2 = *(const f32x4*)(bn2v + c4);
        const f32x4 bg = *(const f32x4*)(bgcm + c4);
        #pragma unroll
        for (int j = 0; j < 4; ++j) {
            ps1[j] = g1[j] * rsqrtf(v1[j] + EPSF);
            pb1[j] = ps1[j] * (bp[j] - m1[j]) + b1[j];
            ps2[j] = g2[j] * rsqrtf(v2[j] + EPSF);
            pb2[j] = ps2[j] * (bg[j] - m2[j]) + b2[j];
        }
    }
    float wat[2][4];
    #pragma unroll
    for (int mt = 0; mt < 2; ++mt)
        #pragma unroll
        for (int r = 0; r < 4; ++r)
            wat[mt][r] = Watt[mt * 16 + quad * 4 + r];
    const float battv = batt[0];

    const f32x4 zero4 = {0.f, 0.f, 0.f, 0.f};
    short* hb = hbuf[w];
    const int base = blockIdx.x * PPB + w * PPW;
    const int bb   = (base >> 14) * N_;

    __syncthreads();   // weight LDS ready

    for (int i = 0; i < PPW; ++i) {
        const int pt = base + i;

        // --- loads (compiler hoists/pipelines across iterations) ---
        int giv[2];
        giv[0] = gidx[(size_t)pt * 32 + l15];
        giv[1] = gidx[(size_t)pt * 32 + 16 + l15];
        const f32x4 resid = *(const f32x4*)(features + (size_t)pt * 64 + c4);
        float xi0, xi1, xi2;
        float px[2], py[2], pz[2];
        if (PAD) {
            const f32x4 x4 = *(const f32x4*)(pp + (size_t)pt * 4);
            xi0 = x4[0]; xi1 = x4[1]; xi2 = x4[2];
            #pragma unroll
            for (int mt = 0; mt < 2; ++mt) {
                const f32x4 p4 = *(const f32x4*)(pp + (size_t)(bb + giv[mt]) * 4);
                px[mt] = p4[0]; py[mt] = p4[1]; pz[mt] = p4[2];
            }
        } else {
            xi0 = points[(size_t)pt * 3];
            xi1 = points[(size_t)pt * 3 + 1];
            xi2 = points[(size_t)pt * 3 + 2];
            #pragma unroll
            for (int mt = 0; mt < 2; ++mt) {
                const float* ppt = points + (size_t)(bb + giv[mt]) * 3;
                px[mt] = ppt[0]; py[mt] = ppt[1]; pz[mt] = ppt[2];
            }
        }
        f32x4 f4[2][4];
        #pragma unroll
        for (int mt = 0; mt < 2; ++mt)
            #pragma unroll
            for (int r = 0; r < 4; ++r) {
                const int gs = __shfl(giv[mt], quad * 4 + r);
                f4[mt][r] = *(const f32x4*)(features + (size_t)(bb + gs) * 64 + c4);
            }

        // --- geo A-frags via packed bf16 converts ---
        bf16x8 ageo[2];
        #pragma unroll
        for (int mt = 0; mt < 2; ++mt) {
            const float dx = xi0 - px[mt], dy = xi1 - py[mt], dz = xi2 - pz[mt];
            const float dist = sqrtf(dx * dx + dy * dy + dz * dz);
            u32x4 u = {0u, 0u, 0u, 0u};
            if (quad == 0) {
                u[0] = pkbf(xi0, xi1); u[1] = pkbf(xi2, px[mt]);
                u[2] = pkbf(py[mt], pz[mt]); u[3] = pkbf(dx, dy);
            } else if (quad == 1) {
                u[0] = pkbf(dz, dist);
            }
            __builtin_memcpy(&ageo[mt], &u, 16);
        }

        // --- pos-MLP MFMA ---
        f32x4 acc1[2][4];
        #pragma unroll
        for (int mt = 0; mt < 2; ++mt)
            #pragma unroll
            for (int nt = 0; nt < 4; ++nt)
                acc1[mt][nt] = __builtin_amdgcn_mfma_f32_16x16x32_bf16(
                    ageo[mt], bposf[nt], zero4, 0, 0, 0);

        // --- epilogue 1: bn1+relu + feature add, packed converts, b64 writes ---
        #pragma unroll
        for (int mt = 0; mt < 2; ++mt)
            #pragma unroll
            for (int r = 0; r < 4; ++r) {
                const int k = mt * 16 + quad * 4 + r;
                float v[4];
                #pragma unroll
                for (int j = 0; j < 4; ++j)
                    v[j] = f4[mt][r][j] + fmaxf(ps1[j] * acc1[mt][j][r] + pb1[j], 0.f);
                u32x2 hv = { pkbf(v[0], v[1]), pkbf(v[2], v[3]) };
                *(u32x2*)&hb[k * HSTR + c4] = hv;
            }

        // --- GCM: A-frags from LDS, B-frags from LDS, 16 MFMAs ---
        bf16x8 a2[2][2];
        #pragma unroll
        for (int mt = 0; mt < 2; ++mt)
            #pragma unroll
            for (int ks = 0; ks < 2; ++ks)
                a2[mt][ks] = *(const bf16x8*)&hb[(mt * 16 + l15) * HSTR + ks * 32 + quad * 8];
        f32x4 acc2[2][4];
        #pragma unroll
        for (int nt = 0; nt < 4; ++nt) {
            const bf16x8 b0 = *(const bf16x8*)&wb2[((nt * 2 + 0) * 64 + l) * 8];
            const bf16x8 b1 = *(const bf16x8*)&wb2[((nt * 2 + 1) * 64 + l) * 8];
            #pragma unroll
            for (int mt = 0; mt < 2; ++mt) {
                f32x4 a = __builtin_amdgcn_mfma_f32_16x16x32_bf16(a2[mt][0], b0, zero4, 0, 0, 0);
                acc2[mt][nt] = __builtin_amdgcn_mfma_f32_16x16x32_bf16(a2[mt][1], b1, a, 0, 0, 0);
            }
        }

        // --- epilogue 2: bn2+relu, attention softmax (shift-invariant), pool ---
        float res[4];
        {
            float sp[4], mk[4];
            #pragma unroll
            for (int nt = 0; nt < 4; ++nt) {
                sp[nt] = 0.f; mk[nt] = 0.f;
                #pragma unroll
                for (int mt = 0; mt < 2; ++mt)
                    #pragma unroll
                    for (int r = 0; r < 4; ++r) {
                        const float h2 = fmaxf(ps2[nt] * acc2[mt][nt][r] + pb2[nt], 0.f);
                        sp[nt] += h2 * wat[mt][r];
                        mk[nt] = fmaxf(mk[nt], h2);
                    }
                sp[nt] += __shfl_xor(sp[nt], 16);
                sp[nt] += __shfl_xor(sp[nt], 32);
                mk[nt] = fmaxf(mk[nt], __shfl_xor(mk[nt], 16));
                mk[nt] = fmaxf(mk[nt], __shfl_xor(mk[nt], 32));
            }
            float e[4], s = 0.f;
            #pragma unroll
            for (int nt = 0; nt < 4; ++nt) { e[nt] = __expf(sp[nt] + battv); s += e[nt]; }
            #pragma unroll
            for (int o = 1; o < 16; o <<= 1) s += __shfl_xor(s, o);
            const float inv = 1.f / s;
            #pragma unroll
            for (int nt = 0; nt < 4; ++nt)
                res[nt] = e[nt] * inv * mk[nt] + resid[nt];
        }
        if (quad == 0) {
            u32x2 rv = { pkbf(res[0], res[1]), pkbf(res[2], res[3]) };
            *(u32x2*)&resstage[(w * PPW + i) * RSTR + c4] = rv;
        }
    }

    __syncthreads();

    // ---------- phase D: batched out-matmul + LayerNorm + relu ----------
    const f32x4 lngv  = *(const f32x4*)(lng + c4);
    const f32x4 lnbv  = *(const f32x4*)(lnb + c4);
    const f32x4 boutv = *(const f32x4*)(bout + c4);
    bf16x8 a3[2];
    #pragma unroll
    for (int ks = 0; ks < 2; ++ks)
        a3[ks] = *(const bf16x8*)&resstage[l15 * RSTR + ks * 32 + quad * 8];
    f32x4 acc3[4];
    #pragma unroll
    for (int nt = 0; nt < 4; ++nt) {
        const bf16x8 b0 = *(const bf16x8*)&wb3[((nt * 2 + 0) * 64 + l) * 8];
        const bf16x8 b1 = *(const bf16x8*)&wb3[((nt * 2 + 1) * 64 + l) * 8];
        f32x4 a = __builtin_amdgcn_mfma_f32_16x16x32_bf16(a3[0], b0, zero4, 0, 0, 0);
        acc3[nt] = __builtin_amdgcn_mfma_f32_16x16x32_bf16(a3[1], b1, a, 0, 0, 0);
    }
    float y[4], s = 0.f;
    #pragma unroll
    for (int nt = 0; nt < 4; ++nt) { y[nt] = acc3[nt][w] + boutv[nt]; s += y[nt]; }
    #pragma unroll
    for (int o = 1; o < 16; o <<= 1) s += __shfl_xor(s, o);
    const float mu = s * (1.f / 64.f);
    float dv[4], v2 = 0.f;
    #pragma unroll
    for (int nt = 0; nt < 4; ++nt) { dv[nt] = y[nt] - mu; v2 += dv[nt] * dv[nt]; }
    #pragma unroll
    for (int o = 1; o < 16; o <<= 1) v2 += __shfl_xor(v2, o);
    const float rs = rsqrtf(v2 * (1.f / 64.f) + EPSF);
    const int pto = blockIdx.x * PPB + quad * 4 + w;
    f32x4 ov;
    #pragma unroll
    for (int nt = 0; nt < 4; ++nt)
        ov[nt] = fmaxf(lngv[nt] * dv[nt] * rs + lnbv[nt], 0.f);
    *(f32x4*)(out + (size_t)pto * 64 + c4) = ov;
}

extern "C" void kernel_launch(void* const* d_in, const int* in_sizes, int n_in,
                              void* d_out, int out_size, void* d_ws, size_t ws_size,
                              hipStream_t stream) {
    const float* points   = (const float*)d_in[0];
    const float* features = (const float*)d_in[1];
    const int*   gidxp    = (const int*)d_in[2];
    const bool   pad      = (ws_size >= PP_BYTES);
    float* pp = (float*)d_ws;
    if (pad) {
        hipLaunchKernelGGL(prep_points, dim3((B_ * N_ + 255) / 256), dim3(256), 0, stream,
                           points, pp);
        hipLaunchKernelGGL((bridgenet6<true>), dim3((B_ * N_) / PPB), dim3(256), 0, stream,
            points, pp, features, gidxp,
            (const float*)d_in[3],  (const float*)d_in[4],
            (const float*)d_in[5],  (const float*)d_in[6],  (const float*)d_in[7],  (const float*)d_in[8],
            (const float*)d_in[9],  (const float*)d_in[10],
            (const float*)d_in[11], (const float*)d_in[12], (const float*)d_in[13], (const float*)d_in[14],
            (const float*)d_in[15], (const float*)d_in[16],
            (const float*)d_in[17], (const float*)d_in[18],
            (const float*)d_in[19], (const float*)d_in[20],
            (float*)d_out);
    } else {
        hipLaunchKernelGGL((bridgenet6<false>), dim3((B_ * N_) / PPB), dim3(256), 0, stream,
            points, pp, features, gidxp,
            (const float*)d_in[3],  (const float*)d_in[4],
            (const float*)d_in[5],  (const float*)d_in[6],  (const float*)d_in[7],  (const float*)d_in[8],
            (const float*)d_in[9],  (const float*)d_in[10],
            (const float*)d_in[11], (const float*)d_in[12], (const float*)d_in[13], (const float*)d_in[14],
            (const float*)d_in[15], (const float*)d_in[16],
            (const float*)d_in[17], (const float*)d_in[18],
            (const float*)d_in[19], (const float*)d_in[20],
            (float*)d_out);
    }
}